// Round 4
// baseline (520.944 us; speedup 1.0000x reference)
//
#include <hip/hip_runtime.h>

#define NPTS 65536
#define NU_F 0.0031830988618379067f

typedef __attribute__((ext_vector_type(8))) short short8v;   // 8 bf16 (4 VGPRs)
typedef __attribute__((ext_vector_type(4))) float float4v;   // MFMA C/D

__device__ __forceinline__ ushort f2bf(float f) {
    union { float f; unsigned u; } v; v.f = f;
    return (ushort)((v.u + 0x7FFFu + ((v.u >> 16) & 1u)) >> 16);   // RNE
}
__device__ __forceinline__ float bf2f(ushort b) {
    union { unsigned u; float f; } v; v.u = ((unsigned)b) << 16;
    return v.f;
}

// tanh jet: a, a'=1-a^2, a''=-2a·a'
__device__ __forceinline__ void jet(float z, float zt, float zx, float zy,
                                    float zxx, float zyy,
                                    float& s0, float& s1, float& s2,
                                    float& s3, float& s4, float& s5) {
    float e  = __expf(2.0f * z);
    float a  = 1.0f - 2.0f * __builtin_amdgcn_rcpf(e + 1.0f);
    float ap = 1.0f - a * a;
    float am = -2.0f * a * ap;
    s0 = a;
    s1 = ap * zt;
    s2 = ap * zx;
    s3 = ap * zy;
    s4 = ap * zxx + am * zx * zx;
    s5 = ap * zyy + am * zy * zy;
}

// ---- LDS jet-matrix access, XOR-swizzled: byte ^= ((sp&7)<<4) ----
__device__ __forceinline__ short8v loadB(const char* baseB, int sp, int k2) {
    return *(const short8v*)(baseB + (((sp << 9) + k2) ^ ((sp & 7) << 4)));
}
__device__ __forceinline__ void storeB(char* baseB, int sp, int jb,
                                       ushort a0, ushort a1, ushort a2, ushort a3) {
    ushort4 v = make_ushort4(a0, a1, a2, a3);
    *(ushort4*)(baseB + (((sp << 9) + (jb << 1)) ^ ((sp & 7) << 4))) = v;
}

// ================= prep: W1..W3 -> bf16 hi/lo in A-fragment order =================
// A-frag for mfma_f32_16x16x32_bf16: lane 16g+r holds A[row r][k = 8g + jj], jj=0..7.
// Amat = W^T (row=j output col, k=input). Frag idx = ((M*8 + kt)*64 + lane), M = j/16.
__global__ __launch_bounds__(256)
void pinn_prep_kernel(const float* __restrict__ W1, const float* __restrict__ W2,
                      const float* __restrict__ W3, ushort* __restrict__ ws) {
    int gid  = blockIdx.x * 256 + threadIdx.x;  // 0..24575
    int l    = gid >> 13;                       // layer 0..2 (8192 threads each)
    int rem  = gid & 8191;
    int M    = rem >> 9;                        // 0..15
    int kt   = (rem >> 6) & 7;                  // 0..7
    int lane = rem & 63;
    const float* W = (l == 0) ? W1 : (l == 1) ? W2 : W3;
    int j  = M * 16 + (lane & 15);
    int k0 = kt * 32 + (lane >> 4) * 8;
    union { ushort u[8]; short8v v; } hi, lo;
    #pragma unroll
    for (int jj = 0; jj < 8; ++jj) {
        float v  = W[(k0 + jj) * 256 + j];      // W[k][j] row-major
        ushort h = f2bf(v);
        hi.u[jj] = h;
        lo.u[jj] = f2bf(v - bf2f(h));
    }
    int off = l * 8192 + ((M * 8 + kt) * 64 + lane);
    ((short8v*)ws)[off]         = hi.v;         // hi frags: [0, 24576)
    ((short8v*)ws)[24576 + off] = lo.v;         // lo frags: [24576, 49152)
}

// ============== main kernel: 16 points / block, 512 threads, 8 waves ==============
// Wave wv owns output cols j in [wv*32, wv*32+32): j-tiles M = wv*2 + m, m in {0,1}.
// amdgpu_waves_per_eu(4,4): LDS (80KB) caps us at 2 blocks/CU = 4 waves/EU anyway;
// pinning max=4 stops the allocator from targeting 8 waves/EU (64 VGPR) and spilling.
__global__ __launch_bounds__(512)
__attribute__((amdgpu_waves_per_eu(4, 4)))
void pinn_burger2d_kernel(
    const float* __restrict__ t, const float* __restrict__ x, const float* __restrict__ y,
    const float* __restrict__ W0, const float* __restrict__ b0,
    const float* __restrict__ b1, const float* __restrict__ b2, const float* __restrict__ b3,
    const float* __restrict__ W4, const float* __restrict__ b4,
    const ushort* __restrict__ wf, float* __restrict__ out)
{
    // Jet matrix (B operand, stored as Ajet[sp][k] bf16): hi 96 rows, lo 64 rows (streams 0-3)
    __shared__ ushort BhiS[96 * 256];   // 48 KiB
    __shared__ ushort BloS[64 * 256];   // 32 KiB
    char* bhiB = (char*)BhiS;
    char* bloB = (char*)BloS;

    const int tid  = threadIdx.x;
    const int lane = tid & 63;
    const int wv   = tid >> 6;      // wave 0..7
    const int p    = lane & 15;     // point 0..15
    const int rg   = lane >> 4;     // 0..3
    const int base = blockIdx.x * 16;
    const int gi   = base + p;

    const float tv = t[gi], xv = x[gi], yv = y[gi];

    // ---------------- layer 0: (t,x,y) -> 256 jet, write to LDS ----------------
    #pragma unroll
    for (int m = 0; m < 2; ++m) {
        const int jb = wv * 32 + m * 16 + rg * 4;
        float4 w0t = *(const float4*)(W0 + jb);
        float4 w0x = *(const float4*)(W0 + 256 + jb);
        float4 w0y = *(const float4*)(W0 + 512 + jb);
        float4 bb  = *(const float4*)(b0 + jb);
        float wtA[4] = {w0t.x, w0t.y, w0t.z, w0t.w};
        float wxA[4] = {w0x.x, w0x.y, w0x.z, w0x.w};
        float wyA[4] = {w0y.x, w0y.y, w0y.z, w0y.w};
        float bbA[4] = {bb.x, bb.y, bb.z, bb.w};
        ushort h[6][4]; ushort lo[4][4];
        #pragma unroll
        for (int r = 0; r < 4; ++r) {
            float z = tv * wtA[r] + xv * wxA[r] + yv * wyA[r] + bbA[r];
            float s0, s1, s2, s3, s4, s5;
            jet(z, wtA[r], wxA[r], wyA[r], 0.0f, 0.0f, s0, s1, s2, s3, s4, s5);
            float ss[6] = {s0, s1, s2, s3, s4, s5};
            #pragma unroll
            for (int s = 0; s < 6; ++s) {
                h[s][r] = f2bf(ss[s]);
                if (s < 4) lo[s][r] = f2bf(ss[s] - bf2f(h[s][r]));
            }
        }
        #pragma unroll
        for (int s = 0; s < 6; ++s)
            storeB(bhiB, s * 16 + p, jb, h[s][0], h[s][1], h[s][2], h[s][3]);
        #pragma unroll
        for (int s = 0; s < 4; ++s)
            storeB(bloB, s * 16 + p, jb, lo[s][0], lo[s][1], lo[s][2], lo[s][3]);
    }
    __syncthreads();

    float4v acc[2][6];

    // ---------------- layers 1..3: MFMA  Z^T = W^T · Ajet^T ----------------
    for (int li = 0; li < 3; ++li) {
        #pragma unroll
        for (int m = 0; m < 2; ++m)
            #pragma unroll
            for (int n = 0; n < 6; ++n) {
                float4v z4 = {0.0f, 0.0f, 0.0f, 0.0f};
                acc[m][n] = z4;
            }

        const short8v* whf = (const short8v*)wf + li * 8192;
        const short8v* wlf = (const short8v*)wf + 24576 + li * 8192;

        for (int kt = 0; kt < 8; ++kt) {
            const int k2  = kt * 64 + rg * 16;
            const int fi0 = (((wv * 2 + 0) * 8 + kt) * 64) + lane;
            const int fi1 = (((wv * 2 + 1) * 8 + kt) * 64) + lane;
            // 4 weight fragments cached for the whole kt step (16 VGPRs)
            short8v wh0 = whf[fi0];
            short8v wl0 = wlf[fi0];
            short8v wh1 = whf[fi1];
            short8v wl1 = wlf[fi1];
            // stream-at-a-time: <=2 B-fragments live at once
            #pragma unroll
            for (int n = 0; n < 6; ++n) {
                short8v bh = loadB(bhiB, n * 16 + p, k2);
                acc[0][n] = __builtin_amdgcn_mfma_f32_16x16x32_bf16(wh0, bh, acc[0][n], 0, 0, 0);
                acc[1][n] = __builtin_amdgcn_mfma_f32_16x16x32_bf16(wh1, bh, acc[1][n], 0, 0, 0);
                acc[0][n] = __builtin_amdgcn_mfma_f32_16x16x32_bf16(wl0, bh, acc[0][n], 0, 0, 0);
                acc[1][n] = __builtin_amdgcn_mfma_f32_16x16x32_bf16(wl1, bh, acc[1][n], 0, 0, 0);
                if (n < 4) {
                    short8v bl = loadB(bloB, n * 16 + p, k2);
                    acc[0][n] = __builtin_amdgcn_mfma_f32_16x16x32_bf16(wh0, bl, acc[0][n], 0, 0, 0);
                    acc[1][n] = __builtin_amdgcn_mfma_f32_16x16x32_bf16(wh1, bl, acc[1][n], 0, 0, 0);
                }
            }
        }
        __syncthreads();   // all waves done reading B before overwrite / reuse

        if (li < 2) {
            const float* bL = (li == 0) ? b1 : b2;
            #pragma unroll
            for (int m = 0; m < 2; ++m) {
                const int jb = wv * 32 + m * 16 + rg * 4;
                float4 bb = *(const float4*)(bL + jb);
                float bbA[4] = {bb.x, bb.y, bb.z, bb.w};
                ushort h[6][4]; ushort lo[4][4];
                #pragma unroll
                for (int r = 0; r < 4; ++r) {
                    float z   = acc[m][0][r] + bbA[r];
                    float s0, s1, s2, s3, s4, s5;
                    jet(z, acc[m][1][r], acc[m][2][r], acc[m][3][r],
                        acc[m][4][r], acc[m][5][r], s0, s1, s2, s3, s4, s5);
                    float ss[6] = {s0, s1, s2, s3, s4, s5};
                    #pragma unroll
                    for (int s = 0; s < 6; ++s) {
                        h[s][r] = f2bf(ss[s]);
                        if (s < 4) lo[s][r] = f2bf(ss[s] - bf2f(h[s][r]));
                    }
                }
                #pragma unroll
                for (int s = 0; s < 6; ++s)
                    storeB(bhiB, s * 16 + p, jb, h[s][0], h[s][1], h[s][2], h[s][3]);
                #pragma unroll
                for (int s = 0; s < 4; ++s)
                    storeB(bloB, s * 16 + p, jb, lo[s][0], lo[s][1], lo[s][2], lo[s][3]);
            }
            __syncthreads();
        }
    }

    // ---------------- layer-3 jet (registers) + final 256->1 dot ----------------
    float part[6] = {0, 0, 0, 0, 0, 0};
    #pragma unroll
    for (int m = 0; m < 2; ++m) {
        const int jb = wv * 32 + m * 16 + rg * 4;
        float4 bb = *(const float4*)(b3 + jb);
        float4 w4 = *(const float4*)(W4 + jb);
        float bbA[4] = {bb.x, bb.y, bb.z, bb.w};
        float w4A[4] = {w4.x, w4.y, w4.z, w4.w};
        #pragma unroll
        for (int r = 0; r < 4; ++r) {
            float z = acc[m][0][r] + bbA[r];
            float s0, s1, s2, s3, s4, s5;
            jet(z, acc[m][1][r], acc[m][2][r], acc[m][3][r],
                acc[m][4][r], acc[m][5][r], s0, s1, s2, s3, s4, s5);
            part[0] += s0 * w4A[r];
            part[1] += s1 * w4A[r];
            part[2] += s2 * w4A[r];
            part[3] += s3 * w4A[r];
            part[4] += s4 * w4A[r];
            part[5] += s5 * w4A[r];
        }
    }
    // reduce over the 4 lanes sharing a point (lane, lane^16, lane^32, lane^48)
    #pragma unroll
    for (int s = 0; s < 6; ++s) {
        part[s] += __shfl_xor(part[s], 16, 64);
        part[s] += __shfl_xor(part[s], 32, 64);
    }
    float* resf = (float*)BloS;   // overlay (Blo no longer needed; barrier above protects)
    if (lane < 16) {
        #pragma unroll
        for (int s = 0; s < 6; ++s) resf[(wv * 6 + s) * 16 + p] = part[s];
    }
    __syncthreads();

    if (tid < 16) {
        const int pp = tid;
        const int g  = base + pp;
        float u = b4[0], ut = 0, ux = 0, uy = 0, uxx = 0, uyy = 0;
        #pragma unroll
        for (int w = 0; w < 8; ++w) {
            u   += resf[(w * 6 + 0) * 16 + pp];
            ut  += resf[(w * 6 + 1) * 16 + pp];
            ux  += resf[(w * 6 + 2) * 16 + pp];
            uy  += resf[(w * 6 + 3) * 16 + pp];
            uxx += resf[(w * 6 + 4) * 16 + pp];
            uyy += resf[(w * 6 + 5) * 16 + pp];
        }
        out[g]        = u;
        out[NPTS + g] = ut + u * ux + u * uy - NU_F * (uxx + uyy);
    }
}

extern "C" void kernel_launch(void* const* d_in, const int* in_sizes, int n_in,
                              void* d_out, int out_size, void* d_ws, size_t ws_size,
                              hipStream_t stream) {
    const float* t  = (const float*)d_in[0];
    const float* x  = (const float*)d_in[1];
    const float* y  = (const float*)d_in[2];
    const float* W0 = (const float*)d_in[3];
    const float* b0 = (const float*)d_in[4];
    const float* W1 = (const float*)d_in[5];
    const float* b1 = (const float*)d_in[6];
    const float* W2 = (const float*)d_in[7];
    const float* b2 = (const float*)d_in[8];
    const float* W3 = (const float*)d_in[9];
    const float* b3 = (const float*)d_in[10];
    const float* W4 = (const float*)d_in[11];
    const float* b4 = (const float*)d_in[12];
    float* out = (float*)d_out;

    pinn_prep_kernel<<<96, 256, 0, stream>>>(W1, W2, W3, (ushort*)d_ws);
    pinn_burger2d_kernel<<<NPTS / 16, 512, 0, stream>>>(
        t, x, y, W0, b0, b1, b2, b3, W4, b4, (const ushort*)d_ws, out);
}

// Round 5
// 362.200 us; speedup vs baseline: 1.4383x; 1.4383x over previous
//
#include <hip/hip_runtime.h>

#define NPTS 65536
#define NU_F 0.0031830988618379067f

typedef __attribute__((ext_vector_type(8))) short short8v;   // 8 bf16 (4 VGPRs)
typedef __attribute__((ext_vector_type(4))) float float4v;   // MFMA C/D

__device__ __forceinline__ ushort f2bf(float f) {
    union { float f; unsigned u; } v; v.f = f;
    return (ushort)((v.u + 0x7FFFu + ((v.u >> 16) & 1u)) >> 16);   // RNE
}
__device__ __forceinline__ float bf2f(ushort b) {
    union { unsigned u; float f; } v; v.u = ((unsigned)b) << 16;
    return v.f;
}

// tanh jet: a, a'=1-a^2, a''=-2a·a'
__device__ __forceinline__ void jet(float z, float zt, float zx, float zy,
                                    float zxx, float zyy,
                                    float& s0, float& s1, float& s2,
                                    float& s3, float& s4, float& s5) {
    float e  = __expf(2.0f * z);
    float a  = 1.0f - 2.0f * __builtin_amdgcn_rcpf(e + 1.0f);
    float ap = 1.0f - a * a;
    float am = -2.0f * a * ap;
    s0 = a;
    s1 = ap * zt;
    s2 = ap * zx;
    s3 = ap * zy;
    s4 = ap * zxx + am * zx * zx;
    s5 = ap * zyy + am * zy * zy;
}

// ---- LDS jet-matrix access, XOR-swizzled: byte ^= ((sp&7)<<4) ----
__device__ __forceinline__ short8v loadB(const char* baseB, int sp, int k2) {
    return *(const short8v*)(baseB + (((sp << 9) + k2) ^ ((sp & 7) << 4)));
}
__device__ __forceinline__ void storeB(char* baseB, int sp, int jb,
                                       ushort a0, ushort a1, ushort a2, ushort a3) {
    ushort4 v = make_ushort4(a0, a1, a2, a3);
    *(ushort4*)(baseB + (((sp << 9) + (jb << 1)) ^ ((sp & 7) << 4))) = v;
}

// ================= prep: W1..W3 -> bf16 hi/lo in A-fragment order =================
// A-frag for mfma_f32_16x16x32_bf16: lane 16g+r holds A[row r][k = 8g + jj], jj=0..7.
// Amat = W^T (row=j output col, k=input). Frag idx = ((M*8 + kt)*64 + lane), M = j/16.
__global__ __launch_bounds__(256)
void pinn_prep_kernel(const float* __restrict__ W1, const float* __restrict__ W2,
                      const float* __restrict__ W3, ushort* __restrict__ ws) {
    int gid  = blockIdx.x * 256 + threadIdx.x;  // 0..24575
    int l    = gid >> 13;                       // layer 0..2 (8192 threads each)
    int rem  = gid & 8191;
    int M    = rem >> 9;                        // 0..15
    int kt   = (rem >> 6) & 7;                  // 0..7
    int lane = rem & 63;
    const float* W = (l == 0) ? W1 : (l == 1) ? W2 : W3;
    int j  = M * 16 + (lane & 15);
    int k0 = kt * 32 + (lane >> 4) * 8;
    union { ushort u[8]; short8v v; } hi, lo;
    #pragma unroll
    for (int jj = 0; jj < 8; ++jj) {
        float v  = W[(k0 + jj) * 256 + j];      // W[k][j] row-major
        ushort h = f2bf(v);
        hi.u[jj] = h;
        lo.u[jj] = f2bf(v - bf2f(h));
    }
    int off = l * 8192 + ((M * 8 + kt) * 64 + lane);
    ((short8v*)ws)[off]         = hi.v;         // hi frags: [0, 24576)
    ((short8v*)ws)[24576 + off] = lo.v;         // lo frags: [24576, 49152)
}

// ============== main kernel: 16 points / block, 512 threads, 8 waves ==============
// Wave wv owns output cols j in [wv*32, wv*32+32): j-tiles M = wv*2 + m, m in {0,1}.
// __launch_bounds__(512, 2): min 2 waves/EU -> VGPR budget 256. The kernel needs
// ~100 VGPRs; the default (no min-waves) budget of 64 caused ~1.2 GB/dispatch of
// scratch spill traffic (R3/R4). LDS (80 KB) caps occupancy at 4 waves/EU anyway.
__global__ __launch_bounds__(512, 2)
void pinn_burger2d_kernel(
    const float* __restrict__ t, const float* __restrict__ x, const float* __restrict__ y,
    const float* __restrict__ W0, const float* __restrict__ b0,
    const float* __restrict__ b1, const float* __restrict__ b2, const float* __restrict__ b3,
    const float* __restrict__ W4, const float* __restrict__ b4,
    const ushort* __restrict__ wf, float* __restrict__ out)
{
    // Jet matrix (B operand, stored as Ajet[sp][k] bf16): hi 96 rows, lo 64 rows (streams 0-3)
    __shared__ ushort BhiS[96 * 256];   // 48 KiB
    __shared__ ushort BloS[64 * 256];   // 32 KiB
    char* bhiB = (char*)BhiS;
    char* bloB = (char*)BloS;

    const int tid  = threadIdx.x;
    const int lane = tid & 63;
    const int wv   = tid >> 6;      // wave 0..7
    const int p    = lane & 15;     // point 0..15
    const int rg   = lane >> 4;     // 0..3
    const int base = blockIdx.x * 16;
    const int gi   = base + p;

    const float tv = t[gi], xv = x[gi], yv = y[gi];

    // ---------------- layer 0: (t,x,y) -> 256 jet, write to LDS ----------------
    #pragma unroll
    for (int m = 0; m < 2; ++m) {
        const int jb = wv * 32 + m * 16 + rg * 4;
        float4 w0t = *(const float4*)(W0 + jb);
        float4 w0x = *(const float4*)(W0 + 256 + jb);
        float4 w0y = *(const float4*)(W0 + 512 + jb);
        float4 bb  = *(const float4*)(b0 + jb);
        float wtA[4] = {w0t.x, w0t.y, w0t.z, w0t.w};
        float wxA[4] = {w0x.x, w0x.y, w0x.z, w0x.w};
        float wyA[4] = {w0y.x, w0y.y, w0y.z, w0y.w};
        float bbA[4] = {bb.x, bb.y, bb.z, bb.w};
        ushort h[6][4]; ushort lo[4][4];
        #pragma unroll
        for (int r = 0; r < 4; ++r) {
            float z = tv * wtA[r] + xv * wxA[r] + yv * wyA[r] + bbA[r];
            float s0, s1, s2, s3, s4, s5;
            jet(z, wtA[r], wxA[r], wyA[r], 0.0f, 0.0f, s0, s1, s2, s3, s4, s5);
            float ss[6] = {s0, s1, s2, s3, s4, s5};
            #pragma unroll
            for (int s = 0; s < 6; ++s) {
                h[s][r] = f2bf(ss[s]);
                if (s < 4) lo[s][r] = f2bf(ss[s] - bf2f(h[s][r]));
            }
        }
        #pragma unroll
        for (int s = 0; s < 6; ++s)
            storeB(bhiB, s * 16 + p, jb, h[s][0], h[s][1], h[s][2], h[s][3]);
        #pragma unroll
        for (int s = 0; s < 4; ++s)
            storeB(bloB, s * 16 + p, jb, lo[s][0], lo[s][1], lo[s][2], lo[s][3]);
    }
    __syncthreads();

    float4v acc[2][6];

    // ---------------- layers 1..3: MFMA  Z^T = W^T · Ajet^T ----------------
    for (int li = 0; li < 3; ++li) {
        #pragma unroll
        for (int m = 0; m < 2; ++m)
            #pragma unroll
            for (int n = 0; n < 6; ++n) {
                float4v z4 = {0.0f, 0.0f, 0.0f, 0.0f};
                acc[m][n] = z4;
            }

        const short8v* whf = (const short8v*)wf + li * 8192;
        const short8v* wlf = (const short8v*)wf + 24576 + li * 8192;

        for (int kt = 0; kt < 8; ++kt) {
            const int k2  = kt * 64 + rg * 16;
            const int fi0 = (((wv * 2 + 0) * 8 + kt) * 64) + lane;
            const int fi1 = (((wv * 2 + 1) * 8 + kt) * 64) + lane;
            // 4 weight fragments cached for the whole kt step (16 VGPRs)
            short8v wh0 = whf[fi0];
            short8v wl0 = wlf[fi0];
            short8v wh1 = whf[fi1];
            short8v wl1 = wlf[fi1];
            // stream-at-a-time: <=2 B-fragments live at once
            #pragma unroll
            for (int n = 0; n < 6; ++n) {
                short8v bh = loadB(bhiB, n * 16 + p, k2);
                acc[0][n] = __builtin_amdgcn_mfma_f32_16x16x32_bf16(wh0, bh, acc[0][n], 0, 0, 0);
                acc[1][n] = __builtin_amdgcn_mfma_f32_16x16x32_bf16(wh1, bh, acc[1][n], 0, 0, 0);
                acc[0][n] = __builtin_amdgcn_mfma_f32_16x16x32_bf16(wl0, bh, acc[0][n], 0, 0, 0);
                acc[1][n] = __builtin_amdgcn_mfma_f32_16x16x32_bf16(wl1, bh, acc[1][n], 0, 0, 0);
                if (n < 4) {
                    short8v bl = loadB(bloB, n * 16 + p, k2);
                    acc[0][n] = __builtin_amdgcn_mfma_f32_16x16x32_bf16(wh0, bl, acc[0][n], 0, 0, 0);
                    acc[1][n] = __builtin_amdgcn_mfma_f32_16x16x32_bf16(wh1, bl, acc[1][n], 0, 0, 0);
                }
            }
        }
        __syncthreads();   // all waves done reading B before overwrite / reuse

        if (li < 2) {
            const float* bL = (li == 0) ? b1 : b2;
            #pragma unroll
            for (int m = 0; m < 2; ++m) {
                const int jb = wv * 32 + m * 16 + rg * 4;
                float4 bb = *(const float4*)(bL + jb);
                float bbA[4] = {bb.x, bb.y, bb.z, bb.w};
                ushort h[6][4]; ushort lo[4][4];
                #pragma unroll
                for (int r = 0; r < 4; ++r) {
                    float z   = acc[m][0][r] + bbA[r];
                    float s0, s1, s2, s3, s4, s5;
                    jet(z, acc[m][1][r], acc[m][2][r], acc[m][3][r],
                        acc[m][4][r], acc[m][5][r], s0, s1, s2, s3, s4, s5);
                    float ss[6] = {s0, s1, s2, s3, s4, s5};
                    #pragma unroll
                    for (int s = 0; s < 6; ++s) {
                        h[s][r] = f2bf(ss[s]);
                        if (s < 4) lo[s][r] = f2bf(ss[s] - bf2f(h[s][r]));
                    }
                }
                #pragma unroll
                for (int s = 0; s < 6; ++s)
                    storeB(bhiB, s * 16 + p, jb, h[s][0], h[s][1], h[s][2], h[s][3]);
                #pragma unroll
                for (int s = 0; s < 4; ++s)
                    storeB(bloB, s * 16 + p, jb, lo[s][0], lo[s][1], lo[s][2], lo[s][3]);
            }
            __syncthreads();
        }
    }

    // ---------------- layer-3 jet (registers) + final 256->1 dot ----------------
    float part[6] = {0, 0, 0, 0, 0, 0};
    #pragma unroll
    for (int m = 0; m < 2; ++m) {
        const int jb = wv * 32 + m * 16 + rg * 4;
        float4 bb = *(const float4*)(b3 + jb);
        float4 w4 = *(const float4*)(W4 + jb);
        float bbA[4] = {bb.x, bb.y, bb.z, bb.w};
        float w4A[4] = {w4.x, w4.y, w4.z, w4.w};
        #pragma unroll
        for (int r = 0; r < 4; ++r) {
            float z = acc[m][0][r] + bbA[r];
            float s0, s1, s2, s3, s4, s5;
            jet(z, acc[m][1][r], acc[m][2][r], acc[m][3][r],
                acc[m][4][r], acc[m][5][r], s0, s1, s2, s3, s4, s5);
            part[0] += s0 * w4A[r];
            part[1] += s1 * w4A[r];
            part[2] += s2 * w4A[r];
            part[3] += s3 * w4A[r];
            part[4] += s4 * w4A[r];
            part[5] += s5 * w4A[r];
        }
    }
    // reduce over the 4 lanes sharing a point (lane, lane^16, lane^32, lane^48)
    #pragma unroll
    for (int s = 0; s < 6; ++s) {
        part[s] += __shfl_xor(part[s], 16, 64);
        part[s] += __shfl_xor(part[s], 32, 64);
    }
    float* resf = (float*)BloS;   // overlay (Blo no longer needed; barrier above protects)
    if (lane < 16) {
        #pragma unroll
        for (int s = 0; s < 6; ++s) resf[(wv * 6 + s) * 16 + p] = part[s];
    }
    __syncthreads();

    if (tid < 16) {
        const int pp = tid;
        const int g  = base + pp;
        float u = b4[0], ut = 0, ux = 0, uy = 0, uxx = 0, uyy = 0;
        #pragma unroll
        for (int w = 0; w < 8; ++w) {
            u   += resf[(w * 6 + 0) * 16 + pp];
            ut  += resf[(w * 6 + 1) * 16 + pp];
            ux  += resf[(w * 6 + 2) * 16 + pp];
            uy  += resf[(w * 6 + 3) * 16 + pp];
            uxx += resf[(w * 6 + 4) * 16 + pp];
            uyy += resf[(w * 6 + 5) * 16 + pp];
        }
        out[g]        = u;
        out[NPTS + g] = ut + u * ux + u * uy - NU_F * (uxx + uyy);
    }
}

extern "C" void kernel_launch(void* const* d_in, const int* in_sizes, int n_in,
                              void* d_out, int out_size, void* d_ws, size_t ws_size,
                              hipStream_t stream) {
    const float* t  = (const float*)d_in[0];
    const float* x  = (const float*)d_in[1];
    const float* y  = (const float*)d_in[2];
    const float* W0 = (const float*)d_in[3];
    const float* b0 = (const float*)d_in[4];
    const float* W1 = (const float*)d_in[5];
    const float* b1 = (const float*)d_in[6];
    const float* W2 = (const float*)d_in[7];
    const float* b2 = (const float*)d_in[8];
    const float* W3 = (const float*)d_in[9];
    const float* b3 = (const float*)d_in[10];
    const float* W4 = (const float*)d_in[11];
    const float* b4 = (const float*)d_in[12];
    float* out = (float*)d_out;

    pinn_prep_kernel<<<96, 256, 0, stream>>>(W1, W2, W3, (ushort*)d_ws);
    pinn_burger2d_kernel<<<NPTS / 16, 512, 0, stream>>>(
        t, x, y, W0, b0, b1, b2, b3, W4, b4, (const ushort*)d_ws, out);
}